// Round 1
// baseline (615.136 us; speedup 1.0000x reference)
//
#include <hip/hip_runtime.h>

// MyLSTM: 2-layer LSTM (input=3, hidden=4) + MLP head (4->4 tanh -> 1), B=4096, T=1024.
// Decomposition: 16 lanes per batch element; lane r = gate row (role=r>>2 in {i,f,g,o},
// unit u=r&3). 65536 threads = 1024 waves = 1 wave/SIMD (max occupancy this problem admits).
// All lanes redundantly hold (c,h) of unit u after each step -> h replicated; recurrent
// dots use 3 shfl_xor + pre-permuted weights W[r, u^k]. Activated gates gathered with 4
// ds_bpermute (addresses precomputed). Activation is uniform per lane: a*sigma(m*x)+b with
// per-lane (m,a,b) encoding sigmoid or tanh. Outputs staged 16 steps then stored coalesced.

#define T_STEPS 1024
#define BATCH   4096

__device__ __forceinline__ float fast_exp2(float x) {
#if __has_builtin(__builtin_amdgcn_exp2f)
    return __builtin_amdgcn_exp2f(x);
#else
    return exp2f(x);
#endif
}

__device__ __forceinline__ float fast_rcp(float x) {
#if __has_builtin(__builtin_amdgcn_rcpf)
    return __builtin_amdgcn_rcpf(x);
#else
    return 1.0f / x;
#endif
}

// tanh(x) = 2*sigmoid(2x) - 1 = 2/(1+exp2(-2.885390x)) - 1
__device__ __forceinline__ float fast_tanh(float x) {
    return 2.0f * fast_rcp(1.0f + fast_exp2(-2.88539008f * x)) - 1.0f;
}

__global__ __launch_bounds__(256) void lstm_fused_kernel(
    const float* __restrict__ x,
    const float* __restrict__ W_ih0, const float* __restrict__ W_hh0,
    const float* __restrict__ b_ih0, const float* __restrict__ b_hh0,
    const float* __restrict__ W_ih1, const float* __restrict__ W_hh1,
    const float* __restrict__ b_ih1, const float* __restrict__ b_hh1,
    const float* __restrict__ W1, const float* __restrict__ b1,
    const float* __restrict__ W2, const float* __restrict__ b2,
    float* __restrict__ out)
{
    const int tid  = threadIdx.x;
    const int lane = tid & 63;
    const int r    = tid & 15;   // gate row 0..15
    const int u    = tid & 3;    // hidden unit 0..3
    const int role = r >> 2;     // 0=i, 1=f, 2=g, 3=o
    const int batch = blockIdx.x * 16 + (tid >> 4);

    // Per-lane activation constants: role g uses tanh = 2*sigma(2x)-1, others sigmoid.
    const float am = (role == 2) ? -2.88539008f : -1.44269504f; // -log2(e)*k
    const float aa = (role == 2) ? 2.0f : 1.0f;
    const float ab = (role == 2) ? -1.0f : 0.0f;

    // Per-lane weight rows (tiny; L1/L2-cached broadcast loads).
    const float wx0 = W_ih0[r * 3 + 0];
    const float wx1 = W_ih0[r * 3 + 1];
    const float wx2 = W_ih0[r * 3 + 2];
    const float bias0 = b_ih0[r] + b_hh0[r];
    const float bias1 = b_ih1[r] + b_hh1[r];

    float wh0[4], wi1[4], wh1[4], w1p[4];
#pragma unroll
    for (int k = 0; k < 4; ++k) {
        wh0[k] = W_hh0[r * 4 + (u ^ k)];
        wi1[k] = W_ih1[r * 4 + (u ^ k)];
        wh1[k] = W_hh1[r * 4 + (u ^ k)];
        w1p[k] = W1[u * 4 + (u ^ k)];
    }
    const float b1u = b1[u];
    const float w2u = W2[u];
    const float b2v = b2[0];

    // bpermute source lanes for gathering activated gates of unit u.
    const int base = lane & 48;
    const int ai = base + u;
    const int af = ai + 4;
    const int ag = ai + 8;
    const int ao = ai + 12;

    float h0 = 0.f, c0 = 0.f, h1 = 0.f, c1 = 0.f;
    float s01 = 0.f, s02 = 0.f, s03 = 0.f;   // h0_{u^1..3} (replicated shuffles)
    float s11 = 0.f, s12 = 0.f, s13 = 0.f;   // h1_{u^1..3}
    float ysave = 0.f;

    const float* xp = x + (size_t)batch * T_STEPS * 3;
    float* op = out + (size_t)batch * T_STEPS;

    for (int t = 0; t < T_STEPS; ++t) {
        const float x0 = xp[0], x1 = xp[1], x2 = xp[2];
        xp += 3;

        // ---- layer 0 ----
        float pre0 = bias0 + wx0 * x0 + wx1 * x1 + wx2 * x2
                   + wh0[0] * h0 + wh0[1] * s01 + wh0[2] * s02 + wh0[3] * s03;
        float a0 = aa * fast_rcp(1.0f + fast_exp2(am * pre0)) + ab;
        float gi = __shfl(a0, ai, 64);
        float gf = __shfl(a0, af, 64);
        float gg = __shfl(a0, ag, 64);
        float go = __shfl(a0, ao, 64);
        c0 = gf * c0 + gi * gg;
        h0 = go * fast_tanh(c0);
        s01 = __shfl_xor(h0, 1, 64);
        s02 = __shfl_xor(h0, 2, 64);
        s03 = __shfl_xor(h0, 3, 64);

        // ---- layer 1 ----
        float pre1 = bias1
                   + wi1[0] * h0 + wi1[1] * s01 + wi1[2] * s02 + wi1[3] * s03
                   + wh1[0] * h1 + wh1[1] * s11 + wh1[2] * s12 + wh1[3] * s13;
        float a1 = aa * fast_rcp(1.0f + fast_exp2(am * pre1)) + ab;
        float gi1 = __shfl(a1, ai, 64);
        float gf1 = __shfl(a1, af, 64);
        float gg1 = __shfl(a1, ag, 64);
        float go1 = __shfl(a1, ao, 64);
        c1 = gf1 * c1 + gi1 * gg1;
        h1 = go1 * fast_tanh(c1);
        s11 = __shfl_xor(h1, 1, 64);
        s12 = __shfl_xor(h1, 2, 64);
        s13 = __shfl_xor(h1, 3, 64);

        // ---- head: y = W2 . tanh(W1 h1 + b1) + b2 ----
        float zp = b1u + w1p[0] * h1 + w1p[1] * s11 + w1p[2] * s12 + w1p[3] * s13;
        float z  = fast_tanh(zp);
        float yv = w2u * z;
        yv += __shfl_xor(yv, 1, 64);
        yv += __shfl_xor(yv, 2, 64);   // all 4 lanes of each unit-quad now hold the sum
        float y = yv + b2v;

        ysave = ((t & 15) == r) ? y : ysave;
        if ((t & 15) == 15) {
            op[(t & ~15) + r] = ysave;   // 16 consecutive floats per group: coalesced
        }
    }
}

extern "C" void kernel_launch(void* const* d_in, const int* in_sizes, int n_in,
                              void* d_out, int out_size, void* d_ws, size_t ws_size,
                              hipStream_t stream) {
    const float* x     = (const float*)d_in[0];
    const float* W_ih0 = (const float*)d_in[1];
    const float* W_hh0 = (const float*)d_in[2];
    const float* b_ih0 = (const float*)d_in[3];
    const float* b_hh0 = (const float*)d_in[4];
    const float* W_ih1 = (const float*)d_in[5];
    const float* W_hh1 = (const float*)d_in[6];
    const float* b_ih1 = (const float*)d_in[7];
    const float* b_hh1 = (const float*)d_in[8];
    const float* W1    = (const float*)d_in[9];
    const float* b1    = (const float*)d_in[10];
    const float* W2    = (const float*)d_in[11];
    const float* b2    = (const float*)d_in[12];
    float* out = (float*)d_out;

    dim3 grid(BATCH / 16);   // 256 blocks
    dim3 block(256);         // 16 batch elements per block, 4 per wave
    lstm_fused_kernel<<<grid, block, 0, stream>>>(
        x, W_ih0, W_hh0, b_ih0, b_hh0, W_ih1, W_hh1, b_ih1, b_hh1,
        W1, b1, W2, b2, out);
}

// Round 2
// 343.789 us; speedup vs baseline: 1.7893x; 1.7893x over previous
//
#include <hip/hip_runtime.h>

// MyLSTM: 2-layer LSTM (input=3, hidden=4) + MLP head (4->4 tanh -> 1), B=4096, T=1024.
//
// R2 redesign: all cross-lane traffic is DPP (pure VALU), zero DS ops.
// Lane layout within each 16-lane group (one batch chain per group):
//   lane l: unit u = (l>>2)&3, role rho = l&3  (rho: 0=i,1=f,2=g,3=o)
//   gate row in W matrices: r = rho*4 + u   (rows 0-3 = i-gates units 0-3, etc.)
// - i/f/g/o gather for unit u: values live in OWN quad -> quad_perm broadcasts.
// - h replication across units (flip lane bits 2-3): row_half_mirror (u^1),
//   row_ror:8 (u^2), row_mirror (u^3) -- XOR patterns, direction-unambiguous.
// - head sum over units: ror8-add + mirror-add.
// Per-lane activation constants (a*sigma(m*x)+b) encode sigmoid vs tanh uniformly.
// x is prefetched 2 steps deep so global-load latency is off the critical path.
// 4096 chains * 16 lanes = 1024 waves = 1 wave/SIMD (max occupancy this problem admits).

#define T_STEPS 1024
#define BATCH   4096

__device__ __forceinline__ float fast_exp2(float x) {
#if __has_builtin(__builtin_amdgcn_exp2f)
    return __builtin_amdgcn_exp2f(x);
#else
    return exp2f(x);
#endif
}

__device__ __forceinline__ float fast_rcp(float x) {
#if __has_builtin(__builtin_amdgcn_rcpf)
    return __builtin_amdgcn_rcpf(x);
#else
    return 1.0f / x;
#endif
}

// tanh(x) = 2*sigmoid(2x) - 1 = 2/(1+exp2(-2.885390x)) - 1
__device__ __forceinline__ float fast_tanh(float x) {
    return 2.0f * fast_rcp(1.0f + fast_exp2(-2.88539008f * x)) - 1.0f;
}

// DPP move: row-scoped lane permute as a VALU op (no LDS crossbar).
template <int CTRL>
__device__ __forceinline__ float dpp_mov(float v) {
    int i = __builtin_bit_cast(int, v);
    i = __builtin_amdgcn_mov_dpp(i, CTRL, 0xF, 0xF, true);
    return __builtin_bit_cast(float, i);
}

#define DPP_QUAD_BCAST0 0x00   // quad_perm [0,0,0,0] -> i gate
#define DPP_QUAD_BCAST1 0x55   // quad_perm [1,1,1,1] -> f gate
#define DPP_QUAD_BCAST2 0xAA   // quad_perm [2,2,2,2] -> g gate
#define DPP_QUAD_BCAST3 0xFF   // quad_perm [3,3,3,3] -> o gate
#define DPP_ROR8        0x128  // lane ^ 8  -> u^2
#define DPP_MIRROR      0x140  // lane ^ 15 -> u^3
#define DPP_HALF_MIRROR 0x141  // lane ^ 7  -> u^1

__global__ __launch_bounds__(256) void lstm_fused_kernel(
    const float* __restrict__ x,
    const float* __restrict__ W_ih0, const float* __restrict__ W_hh0,
    const float* __restrict__ b_ih0, const float* __restrict__ b_hh0,
    const float* __restrict__ W_ih1, const float* __restrict__ W_hh1,
    const float* __restrict__ b_ih1, const float* __restrict__ b_hh1,
    const float* __restrict__ W1, const float* __restrict__ b1,
    const float* __restrict__ W2, const float* __restrict__ b2,
    float* __restrict__ out)
{
    const int tid  = threadIdx.x;
    const int idx  = tid & 15;          // lane within 16-lane group
    const int rho  = tid & 3;           // role: 0=i,1=f,2=g,3=o
    const int u    = (tid >> 2) & 3;    // hidden unit
    const int r    = rho * 4 + u;       // gate row in the 16-row weight matrices
    const int batch = blockIdx.x * 16 + (tid >> 4);

    // Per-lane activation constants: role g (rho==2) uses tanh = 2*sigma(2x)-1.
    const float am = (rho == 2) ? -2.88539008f : -1.44269504f;
    const float aa = (rho == 2) ? 2.0f : 1.0f;
    const float ab = (rho == 2) ? -1.0f : 0.0f;

    // Per-lane weight rows (tiny; L1/L2-cached broadcast loads).
    const float wx0 = W_ih0[r * 3 + 0];
    const float wx1 = W_ih0[r * 3 + 1];
    const float wx2 = W_ih0[r * 3 + 2];
    const float bias0 = b_ih0[r] + b_hh0[r];
    const float bias1 = b_ih1[r] + b_hh1[r];

    float wh0[4], wi1[4], wh1[4], w1p[4];
#pragma unroll
    for (int k = 0; k < 4; ++k) {
        wh0[k] = W_hh0[r * 4 + (u ^ k)];   // order: own, ^1, ^2, ^3
        wi1[k] = W_ih1[r * 4 + (u ^ k)];
        wh1[k] = W_hh1[r * 4 + (u ^ k)];
        w1p[k] = W1[u * 4 + (u ^ k)];
    }
    const float b1u = b1[u];
    const float w2u = W2[u];
    const float b2v = b2[0];

    float h0 = 0.f, c0 = 0.f, h1 = 0.f, c1 = 0.f;
    float h0b = 0.f, h0c = 0.f, h0d = 0.f;   // h0 of units u^1, u^2, u^3
    float h1b = 0.f, h1c = 0.f, h1d = 0.f;
    float ysave = 0.f;

    const float* xp = x + (size_t)batch * T_STEPS * 3;
    float* op = out + (size_t)batch * T_STEPS;

    // 2-deep x prefetch pipeline: loads issued ~2 iterations before use.
    float ax0 = xp[0], ax1 = xp[1], ax2 = xp[2];
    float bx0 = xp[3], bx1 = xp[4], bx2 = xp[5];
    xp += 6;

#pragma unroll 2
    for (int t = 0; t < T_STEPS; ++t) {
        const float x0 = ax0, x1 = ax1, x2 = ax2;
        ax0 = bx0; ax1 = bx1; ax2 = bx2;
        // Prefetch x for step t+2 (clamped at the tail; clamped loads are dead).
        const float* xl = (t < T_STEPS - 2) ? xp : (xp - 6);
        bx0 = xl[0]; bx1 = xl[1]; bx2 = xl[2];
        xp += 3;

        // ---- layer 0 ----
        float pre0 = bias0 + wx0 * x0 + wx1 * x1 + wx2 * x2
                   + wh0[0] * h0 + wh0[1] * h0b + wh0[2] * h0c + wh0[3] * h0d;
        float a0 = aa * fast_rcp(1.0f + fast_exp2(am * pre0)) + ab;
        float gi = dpp_mov<DPP_QUAD_BCAST0>(a0);
        float gf = dpp_mov<DPP_QUAD_BCAST1>(a0);
        float gg = dpp_mov<DPP_QUAD_BCAST2>(a0);
        float go = dpp_mov<DPP_QUAD_BCAST3>(a0);
        c0 = gf * c0 + gi * gg;
        h0 = go * fast_tanh(c0);
        h0b = dpp_mov<DPP_HALF_MIRROR>(h0);
        h0c = dpp_mov<DPP_ROR8>(h0);
        h0d = dpp_mov<DPP_MIRROR>(h0);

        // ---- layer 1 ----
        float pre1 = bias1
                   + wi1[0] * h0 + wi1[1] * h0b + wi1[2] * h0c + wi1[3] * h0d
                   + wh1[0] * h1 + wh1[1] * h1b + wh1[2] * h1c + wh1[3] * h1d;
        float a1 = aa * fast_rcp(1.0f + fast_exp2(am * pre1)) + ab;
        float gi1 = dpp_mov<DPP_QUAD_BCAST0>(a1);
        float gf1 = dpp_mov<DPP_QUAD_BCAST1>(a1);
        float gg1 = dpp_mov<DPP_QUAD_BCAST2>(a1);
        float go1 = dpp_mov<DPP_QUAD_BCAST3>(a1);
        c1 = gf1 * c1 + gi1 * gg1;
        h1 = go1 * fast_tanh(c1);
        h1b = dpp_mov<DPP_HALF_MIRROR>(h1);
        h1c = dpp_mov<DPP_ROR8>(h1);
        h1d = dpp_mov<DPP_MIRROR>(h1);

        // ---- head: y = W2 . tanh(W1 h1 + b1) + b2 ----
        float zp = b1u + w1p[0] * h1 + w1p[1] * h1b + w1p[2] * h1c + w1p[3] * h1d;
        float z  = fast_tanh(zp);
        float yv = w2u * z;                       // quad-uniform
        float t1 = yv + dpp_mov<DPP_ROR8>(yv);    // + unit u^2
        float y  = t1 + dpp_mov<DPP_MIRROR>(t1) + b2v;  // + units u^1,u^3 -> full sum

        ysave = ((t & 15) == idx) ? y : ysave;
        if ((t & 15) == 15) {
            op[(t & ~15) + idx] = ysave;   // 16 consecutive floats per group: coalesced
        }
    }
}

extern "C" void kernel_launch(void* const* d_in, const int* in_sizes, int n_in,
                              void* d_out, int out_size, void* d_ws, size_t ws_size,
                              hipStream_t stream) {
    const float* x     = (const float*)d_in[0];
    const float* W_ih0 = (const float*)d_in[1];
    const float* W_hh0 = (const float*)d_in[2];
    const float* b_ih0 = (const float*)d_in[3];
    const float* b_hh0 = (const float*)d_in[4];
    const float* W_ih1 = (const float*)d_in[5];
    const float* W_hh1 = (const float*)d_in[6];
    const float* b_ih1 = (const float*)d_in[7];
    const float* b_hh1 = (const float*)d_in[8];
    const float* W1    = (const float*)d_in[9];
    const float* b1    = (const float*)d_in[10];
    const float* W2    = (const float*)d_in[11];
    const float* b2    = (const float*)d_in[12];
    float* out = (float*)d_out;

    dim3 grid(BATCH / 16);   // 256 blocks
    dim3 block(256);         // 16 batch elements per block, 4 chains per wave
    lstm_fused_kernel<<<grid, block, 0, stream>>>(
        x, W_ih0, W_hh0, b_ih0, b_hh0, W_ih1, W_hh1, b_ih1, b_hh1,
        W1, b1, W2, b2, out);
}

// Round 3
// 279.819 us; speedup vs baseline: 2.1983x; 1.2286x over previous
//
#include <hip/hip_runtime.h>

// MyLSTM: 2-layer LSTM (input=3, hidden=4) + MLP head (4->4 tanh -> 1), B=4096, T=1024.
//
// R3: layer-pipeline parallelism. Each block = 128 threads = 2 waves, 4 chains.
//   wave 0 (producer): layer-0 LSTM for its 4 chains
//   wave 1 (consumer): layer-1 LSTM + MLP head + output store for the same 4 chains
// h0 flows producer->consumer through a double-buffered LDS ring of 16-step chunks
// (one __syncthreads per chunk). 2048 waves = 2 waves/SIMD: the two waves' dependency
// stalls interleave, converting the R2 stall-bound 675 cyc/step into issue-bound ~350.
//
// Lane layout within each 16-lane group (one chain): unit u=(l>>2)&3, role rho=l&3
// (0=i,1=f,2=g,3=o); gate row r = rho*4+u. All cross-lane traffic is DPP:
// quad_perm broadcasts gather i/f/g/o; half_mirror/ror8/mirror replicate h across units.
// Producer writes the replicated quad {h0,h0^1,h0^2,h0^3} as one ds_write_b128;
// consumer ds_read_b128 (1-step prefetch) needs no replication DPPs.

#define T_STEPS 1024
#define BATCH   4096
#define CHUNK   16
#define NCHUNK  (T_STEPS / CHUNK)

__device__ __forceinline__ float fast_exp2(float x) {
#if __has_builtin(__builtin_amdgcn_exp2f)
    return __builtin_amdgcn_exp2f(x);
#else
    return exp2f(x);
#endif
}

__device__ __forceinline__ float fast_rcp(float x) {
#if __has_builtin(__builtin_amdgcn_rcpf)
    return __builtin_amdgcn_rcpf(x);
#else
    return 1.0f / x;
#endif
}

// tanh(x) = 2*sigmoid(2x) - 1 = 2/(1+exp2(-2.885390x)) - 1
__device__ __forceinline__ float fast_tanh(float x) {
    return 2.0f * fast_rcp(1.0f + fast_exp2(-2.88539008f * x)) - 1.0f;
}

template <int CTRL>
__device__ __forceinline__ float dpp_mov(float v) {
    int i = __builtin_bit_cast(int, v);
    i = __builtin_amdgcn_mov_dpp(i, CTRL, 0xF, 0xF, true);
    return __builtin_bit_cast(float, i);
}

#define DPP_QUAD_BCAST0 0x00   // quad_perm [0,0,0,0] -> i gate
#define DPP_QUAD_BCAST1 0x55   // quad_perm [1,1,1,1] -> f gate
#define DPP_QUAD_BCAST2 0xAA   // quad_perm [2,2,2,2] -> g gate
#define DPP_QUAD_BCAST3 0xFF   // quad_perm [3,3,3,3] -> o gate
#define DPP_ROR8        0x128  // lane ^ 8  -> u^2
#define DPP_MIRROR      0x140  // lane ^ 15 -> u^3
#define DPP_HALF_MIRROR 0x141  // lane ^ 7  -> u^1

__global__ __launch_bounds__(128) void lstm_pipe_kernel(
    const float* __restrict__ x,
    const float* __restrict__ W_ih0, const float* __restrict__ W_hh0,
    const float* __restrict__ b_ih0, const float* __restrict__ b_hh0,
    const float* __restrict__ W_ih1, const float* __restrict__ W_hh1,
    const float* __restrict__ b_ih1, const float* __restrict__ b_hh1,
    const float* __restrict__ W1, const float* __restrict__ b1,
    const float* __restrict__ W2, const float* __restrict__ b2,
    float* __restrict__ out)
{
    // h0 ring: [2 slots][16 steps][64 lanes] float4 = 32 KB
    __shared__ float4 ring[2][CHUNK][64];

    const int tid  = threadIdx.x;
    const int wv   = tid >> 6;          // 0 = producer (layer 0), 1 = consumer (layer 1 + head)
    const int lane = tid & 63;
    const int idx  = lane & 15;         // lane within 16-lane chain group
    const int rho  = lane & 3;          // role: 0=i,1=f,2=g,3=o
    const int u    = (lane >> 2) & 3;   // hidden unit
    const int r    = rho * 4 + u;       // gate row in the 16-row weight matrices
    const int batch = blockIdx.x * 4 + (lane >> 4);

    // Per-lane activation constants: role g (rho==2) uses tanh = 2*sigma(2x)-1.
    const float am = (rho == 2) ? -2.88539008f : -1.44269504f;
    const float aa = (rho == 2) ? 2.0f : 1.0f;
    const float ab = (rho == 2) ? -1.0f : 0.0f;

    // ---- producer constants ----
    const float wx0 = W_ih0[r * 3 + 0];
    const float wx1 = W_ih0[r * 3 + 1];
    const float wx2 = W_ih0[r * 3 + 2];
    const float bias0 = b_ih0[r] + b_hh0[r];
    float wh0[4];
#pragma unroll
    for (int k = 0; k < 4; ++k) wh0[k] = W_hh0[r * 4 + (u ^ k)];

    // ---- consumer constants ----
    const float bias1 = b_ih1[r] + b_hh1[r];
    float wi1[4], wh1[4], w1p[4];
#pragma unroll
    for (int k = 0; k < 4; ++k) {
        wi1[k] = W_ih1[r * 4 + (u ^ k)];
        wh1[k] = W_hh1[r * 4 + (u ^ k)];
        w1p[k] = W1[u * 4 + (u ^ k)];
    }
    const float b1u = b1[u];
    const float w2u = W2[u];
    const float b2v = b2[0];

    // ---- producer state ----
    float h0 = 0.f, c0 = 0.f, h0b = 0.f, h0c = 0.f, h0d = 0.f;
    const float* xp = x + (size_t)batch * T_STEPS * 3;
    float ax0 = 0.f, ax1 = 0.f, ax2 = 0.f, bx0 = 0.f, bx1 = 0.f, bx2 = 0.f;
    if (wv == 0) {   // prime 2-deep x prefetch
        ax0 = xp[0]; ax1 = xp[1]; ax2 = xp[2];
        bx0 = xp[3]; bx1 = xp[4]; bx2 = xp[5];
        xp += 6;
    }

    // ---- consumer state ----
    float h1 = 0.f, c1 = 0.f, h1b = 0.f, h1c = 0.f, h1d = 0.f;
    float ysave = 0.f;
    float* op = out + (size_t)batch * T_STEPS;

    for (int c = 0; c < NCHUNK; ++c) {
        if (wv == 0) {
            // ================= producer: layer 0, chunk c =================
            float4* rg = &ring[c & 1][0][lane];
#pragma unroll
            for (int tt = 0; tt < CHUNK; ++tt) {
                const int t = c * CHUNK + tt;
                const float x0 = ax0, x1 = ax1, x2 = ax2;
                ax0 = bx0; ax1 = bx1; ax2 = bx2;
                const float* xl = (t < T_STEPS - 2) ? xp : (xp - 6);
                bx0 = xl[0]; bx1 = xl[1]; bx2 = xl[2];
                xp += 3;

                float pre0 = bias0 + wx0 * x0 + wx1 * x1 + wx2 * x2
                           + wh0[0] * h0 + wh0[1] * h0b + wh0[2] * h0c + wh0[3] * h0d;
                float a0 = aa * fast_rcp(1.0f + fast_exp2(am * pre0)) + ab;
                float gi = dpp_mov<DPP_QUAD_BCAST0>(a0);
                float gf = dpp_mov<DPP_QUAD_BCAST1>(a0);
                float gg = dpp_mov<DPP_QUAD_BCAST2>(a0);
                float go = dpp_mov<DPP_QUAD_BCAST3>(a0);
                c0 = gf * c0 + gi * gg;
                h0 = go * fast_tanh(c0);
                h0b = dpp_mov<DPP_HALF_MIRROR>(h0);
                h0c = dpp_mov<DPP_ROR8>(h0);
                h0d = dpp_mov<DPP_MIRROR>(h0);

                rg[tt * 64] = make_float4(h0, h0b, h0c, h0d);
            }
        } else if (c >= 1) {
            // ================= consumer: layer 1 + head, chunk c-1 =================
            const int cc = c - 1;
            const float4* rg = &ring[cc & 1][0][lane];
            float4 hcur = rg[0];
#pragma unroll
            for (int tt = 0; tt < CHUNK; ++tt) {
                // 1-step LDS prefetch (clamped; dead value on last step)
                float4 hnxt = rg[((tt < CHUNK - 1) ? tt + 1 : tt) * 64];

                float pre1 = bias1
                           + wi1[0] * hcur.x + wi1[1] * hcur.y + wi1[2] * hcur.z + wi1[3] * hcur.w
                           + wh1[0] * h1 + wh1[1] * h1b + wh1[2] * h1c + wh1[3] * h1d;
                float a1 = aa * fast_rcp(1.0f + fast_exp2(am * pre1)) + ab;
                float gi1 = dpp_mov<DPP_QUAD_BCAST0>(a1);
                float gf1 = dpp_mov<DPP_QUAD_BCAST1>(a1);
                float gg1 = dpp_mov<DPP_QUAD_BCAST2>(a1);
                float go1 = dpp_mov<DPP_QUAD_BCAST3>(a1);
                c1 = gf1 * c1 + gi1 * gg1;
                h1 = go1 * fast_tanh(c1);
                h1b = dpp_mov<DPP_HALF_MIRROR>(h1);
                h1c = dpp_mov<DPP_ROR8>(h1);
                h1d = dpp_mov<DPP_MIRROR>(h1);

                // head: y = W2 . tanh(W1 h1 + b1) + b2
                float zp = b1u + w1p[0] * h1 + w1p[1] * h1b + w1p[2] * h1c + w1p[3] * h1d;
                float z  = fast_tanh(zp);
                float yv = w2u * z;                              // quad-uniform
                float t1 = yv + dpp_mov<DPP_ROR8>(yv);           // + unit u^2
                float y  = t1 + dpp_mov<DPP_MIRROR>(t1) + b2v;   // + units u^1,u^3

                ysave = (tt == idx) ? y : ysave;
                hcur = hnxt;
            }
            op[cc * CHUNK + idx] = ysave;   // 16 consecutive floats per chain: coalesced
        }
        __syncthreads();
    }

    // final chunk: consumer drains chunk NCHUNK-1
    if (wv == 1) {
        const int cc = NCHUNK - 1;
        const float4* rg = &ring[cc & 1][0][lane];
        float4 hcur = rg[0];
#pragma unroll
        for (int tt = 0; tt < CHUNK; ++tt) {
            float4 hnxt = rg[((tt < CHUNK - 1) ? tt + 1 : tt) * 64];

            float pre1 = bias1
                       + wi1[0] * hcur.x + wi1[1] * hcur.y + wi1[2] * hcur.z + wi1[3] * hcur.w
                       + wh1[0] * h1 + wh1[1] * h1b + wh1[2] * h1c + wh1[3] * h1d;
            float a1 = aa * fast_rcp(1.0f + fast_exp2(am * pre1)) + ab;
            float gi1 = dpp_mov<DPP_QUAD_BCAST0>(a1);
            float gf1 = dpp_mov<DPP_QUAD_BCAST1>(a1);
            float gg1 = dpp_mov<DPP_QUAD_BCAST2>(a1);
            float go1 = dpp_mov<DPP_QUAD_BCAST3>(a1);
            c1 = gf1 * c1 + gi1 * gg1;
            h1 = go1 * fast_tanh(c1);
            h1b = dpp_mov<DPP_HALF_MIRROR>(h1);
            h1c = dpp_mov<DPP_ROR8>(h1);
            h1d = dpp_mov<DPP_MIRROR>(h1);

            float zp = b1u + w1p[0] * h1 + w1p[1] * h1b + w1p[2] * h1c + w1p[3] * h1d;
            float z  = fast_tanh(zp);
            float yv = w2u * z;
            float t1 = yv + dpp_mov<DPP_ROR8>(yv);
            float y  = t1 + dpp_mov<DPP_MIRROR>(t1) + b2v;

            ysave = (tt == idx) ? y : ysave;
            hcur = hnxt;
        }
        op[cc * CHUNK + idx] = ysave;
    }
}

extern "C" void kernel_launch(void* const* d_in, const int* in_sizes, int n_in,
                              void* d_out, int out_size, void* d_ws, size_t ws_size,
                              hipStream_t stream) {
    const float* x     = (const float*)d_in[0];
    const float* W_ih0 = (const float*)d_in[1];
    const float* W_hh0 = (const float*)d_in[2];
    const float* b_ih0 = (const float*)d_in[3];
    const float* b_hh0 = (const float*)d_in[4];
    const float* W_ih1 = (const float*)d_in[5];
    const float* W_hh1 = (const float*)d_in[6];
    const float* b_ih1 = (const float*)d_in[7];
    const float* b_hh1 = (const float*)d_in[8];
    const float* W1    = (const float*)d_in[9];
    const float* b1    = (const float*)d_in[10];
    const float* W2    = (const float*)d_in[11];
    const float* b2    = (const float*)d_in[12];
    float* out = (float*)d_out;

    dim3 grid(BATCH / 4);    // 1024 blocks, 4 chains each
    dim3 block(128);         // 2 waves: producer (layer 0) + consumer (layer 1 + head)
    lstm_pipe_kernel<<<grid, block, 0, stream>>>(
        x, W_ih0, W_hh0, b_ih0, b_hh0, W_ih1, W_hh1, b_ih1, b_hh1,
        W1, b1, W2, b2, out);
}